// Round 5
// baseline (102.099 us; speedup 1.0000x reference)
//
#include <hip/hip_runtime.h>

typedef unsigned short u16;
typedef __attribute__((ext_vector_type(8))) __bf16 bf16x8;
typedef __attribute__((ext_vector_type(4))) float f32x4;

#define DI __device__ __forceinline__

DI u16 f2b(float f){ union{float f; unsigned u;} x; x.f = f; unsigned u = x.u;
  return (u16)((u + 0x7FFFu + ((u>>16)&1u)) >> 16); }

DI void gload16(const void* g, void* l) {
  __builtin_amdgcn_global_load_lds(
      (const __attribute__((address_space(1))) void*)g,
      (__attribute__((address_space(3))) void*)l, 16, 0, 0);
}

#define NCH 16   // number of chunks
#define CLEN 64  // chunk length  (NCH*CLEN == L == 1024)

// ---------------- prep: cast x->bf16 (blocks 0..511) + 5 weight transposes ----------------
__global__ __launch_bounds__(256) void k_prep(const float* __restrict__ x, u16* __restrict__ xb,
                            const float* w0, const float* w1, const float* w2, const float* w3, const float* w4,
                            u16* t0, u16* t1, u16* t2, u16* t3, u16* t4) {
  __shared__ u16 tile[32][33];
  int z = blockIdx.x;
  int t = threadIdx.x;
  if (z < 512) {
    int i = (z*256 + t)*8;
    float4 a = *(const float4*)(x+i);
    float4 b = *(const float4*)(x+i+4);
    unsigned o0 = (unsigned)f2b(a.x) | ((unsigned)f2b(a.y)<<16);
    unsigned o1 = (unsigned)f2b(a.z) | ((unsigned)f2b(a.w)<<16);
    unsigned o2 = (unsigned)f2b(b.x) | ((unsigned)f2b(b.y)<<16);
    unsigned o3 = (unsigned)f2b(b.z) | ((unsigned)f2b(b.w)<<16);
    *(uint4*)(xb+i) = make_uint4(o0,o1,o2,o3);
    return;
  }
  z -= 512;
  int which = z >> 8;       // 0..4
  int rem = z & 255;
  const float* src; u16* dst; int K, N;
  if (which==0){src=w0;dst=t0;K=512;N=512;}
  else if(which==1){src=w1;dst=t1;K=512;N=512;}
  else if(which==2){src=w2;dst=t2;K=512;N=512;}
  else if(which==3){src=w3;dst=t3;K=512;N=256;}
  else             {src=w4;dst=t4;K=512;N=512;}
  int n0 = (rem & 15)*32, k0 = (rem >> 4)*32;
  if (n0 >= N) return;
  int tx = t & 31, ty = t >> 5; // 32 x 8
  #pragma unroll
  for (int r = 0; r < 4; r++) tile[ty + 8*r][tx] = f2b(src[(k0 + ty + 8*r)*N + n0 + tx]);
  __syncthreads();
  #pragma unroll
  for (int r = 0; r < 4; r++) dst[(n0 + ty + 8*r)*K + k0 + tx] = tile[tx][ty + 8*r];
}

// ============ 128x128-tile MFMA mainloop (BK=32, global_load_lds, 2-phase) ============
// smem layout per buf: A[128][32] bf16 (4096 shorts) then B[128][32] (4096 shorts).
// 4 waves, each owns a 64x64 output quadrant: acc[4][4] of 16x16 fragments.
#define GEMM_MAINLOOP(A_, BT_, K_, bm_, bn_)                                           \
  __shared__ short smem[2][8192];                                                      \
  int t = threadIdx.x;                                                                 \
  int lane = t & 63, wid = t >> 6;                                                     \
  int lr = lane & 15, ls = lane >> 4;                                                  \
  int wm = (wid>>1)*64, wn = (wid&1)*64;                                               \
  f32x4 acc[4][4];                                                                     \
  {f32x4 z_ = {0.f,0.f,0.f,0.f};                                                       \
   _Pragma("unroll") for (int i_=0;i_<4;i_++) _Pragma("unroll") for (int j_=0;j_<4;j_++) acc[i_][j_]=z_;} \
  int rr_ = t >> 2, cc_ = (t & 3)*8;                                                   \
  const u16* gpa0_ = A_  + (bm_ + rr_)*K_      + cc_;                                  \
  const u16* gpa1_ = A_  + (bm_ + 64 + rr_)*K_ + cc_;                                  \
  const u16* gpb0_ = BT_ + (bn_ + rr_)*K_      + cc_;                                  \
  const u16* gpb1_ = BT_ + (bn_ + 64 + rr_)*K_ + cc_;                                  \
  int woff_ = wid*512;                                                                 \
  /* prologue stage into buf 0 */                                                      \
  { short* lb_ = &smem[0][woff_];                                                      \
    gload16(gpa0_, lb_); gload16(gpa1_, lb_+2048);                                     \
    gload16(gpb0_, lb_+4096); gload16(gpb1_, lb_+6144); }                              \
  __syncthreads();                                                                     \
  const int NSTEP_ = (K_)/32;                                                          \
  for (int st_ = 0; st_ < NSTEP_; st_++) {                                             \
    int buf_ = st_ & 1;                                                                \
    if (st_ + 1 < NSTEP_) {                                                            \
      int kk_ = (st_+1)*32;                                                            \
      short* lb_ = &smem[buf_^1][woff_];                                               \
      gload16(gpa0_+kk_, lb_); gload16(gpa1_+kk_, lb_+2048);                           \
      gload16(gpb0_+kk_, lb_+4096); gload16(gpb1_+kk_, lb_+6144);                      \
    }                                                                                  \
    bf16x8 afr_[4], bfr_[4];                                                           \
    _Pragma("unroll")                                                                  \
    for (int mi = 0; mi < 4; mi++)                                                     \
      afr_[mi] = *(const bf16x8*)&smem[buf_][(wm + mi*16 + lr)*32 + ls*8];             \
    _Pragma("unroll")                                                                  \
    for (int ni = 0; ni < 4; ni++)                                                     \
      bfr_[ni] = *(const bf16x8*)&smem[buf_][4096 + (wn + ni*16 + lr)*32 + ls*8];      \
    _Pragma("unroll")                                                                  \
    for (int mi = 0; mi < 4; mi++)                                                     \
      _Pragma("unroll")                                                                \
      for (int ni = 0; ni < 4; ni++)                                                   \
        acc[mi][ni] = __builtin_amdgcn_mfma_f32_16x16x32_bf16(afr_[mi], bfr_[ni], acc[mi][ni], 0,0,0); \
    __syncthreads();                                                                   \
  }

// ---------------- fused first-layer GEMM over concatenated BT [1792][512] ----------------
__global__ __launch_bounds__(256) void k_gemm4(const u16* __restrict__ A, const u16* __restrict__ BTF,
                       const float* __restrict__ kb1, const float* __restrict__ qb1,
                       const float* __restrict__ vb,  const float* __restrict__ gbias1,
                       float* __restrict__ Hke, float* __restrict__ Hqe,
                       float* __restrict__ V,   float* __restrict__ Hg) {
  int bm = blockIdx.y*128, bn = blockIdx.x*128;
  GEMM_MAINLOOP(A, BTF, 512, bm, bn)
  float* C; const float* bias; int nstr, nb; bool gel;
  if (bn < 512)       { C=Hke; bias=kb1;    nstr=512; nb=bn;      gel=true;  }
  else if (bn < 1024) { C=Hqe; bias=qb1;    nstr=512; nb=bn-512;  gel=true;  }
  else if (bn < 1536) { C=V;   bias=vb;     nstr=512; nb=bn-1024; gel=false; }
  else                { C=Hg;  bias=gbias1; nstr=256; nb=bn-1536; gel=true;  }
  #pragma unroll
  for (int mi = 0; mi < 4; mi++)
    #pragma unroll
    for (int ni = 0; ni < 4; ni++)
      #pragma unroll
      for (int r = 0; r < 4; r++) {
        int grow = bm + wm + mi*16 + ls*4 + r;
        int gcol = nb + wn + ni*16 + lr;
        float v = acc[mi][ni][r] + bias[gcol];
        if (gel) v = 0.5f*v*(1.0f + erff(v*0.70710678118654752f));
        C[grow*nstr + gcol] = v;
      }
}

// ---------------- final GEMM: out = resid + hln @ oT + bias ----------------
__global__ __launch_bounds__(256) void k_gemm_out(const u16* __restrict__ A, const u16* __restrict__ BT,
                       const float* __restrict__ bias, const float* __restrict__ resid,
                       float* __restrict__ C) {
  int bm = blockIdx.y*128, bn = blockIdx.x*128;
  GEMM_MAINLOOP(A, BT, 512, bm, bn)
  #pragma unroll
  for (int mi = 0; mi < 4; mi++)
    #pragma unroll
    for (int ni = 0; ni < 4; ni++)
      #pragma unroll
      for (int r = 0; r < 4; r++) {
        int grow = bm + wm + mi*16 + ls*4 + r;
        int gcol = bn + wn + ni*16 + lr;
        float v = acc[mi][ni][r] + bias[gcol] + resid[grow*512 + gcol];
        C[grow*512 + gcol] = v;
      }
}

// ---------------- phases / features: one wave per row ----------------
__global__ __launch_bounds__(256) void k_phase(const float* __restrict__ Hke, const float* __restrict__ Hqe,
                        const float* __restrict__ Hg,
                        const float* __restrict__ kw2, const float* __restrict__ kb2,
                        const float* __restrict__ qw2, const float* __restrict__ qb2,
                        const float* __restrict__ gw2, const float* __restrict__ gb2,
                        const float* __restrict__ setw, const float* __restrict__ posw,
                        const float* __restrict__ freqs,
                        float* __restrict__ ub, float* __restrict__ ab) {
  int t = threadIdx.x;
  int wid = t >> 6, lane = t & 63;
  int r = blockIdx.x*4 + wid;
  int l = r & 1023;
  int p = lane & 15, s = lane >> 4;
  const float* hk = Hke + r*512 + s*128;
  const float* hq = Hqe + r*512 + s*128;
  float kps = 0.f, qps = 0.f;
  for (int i0 = 0; i0 < 128; i0 += 4) {
    float4 hkv = *(const float4*)(hk + i0);
    float4 hqv = *(const float4*)(hq + i0);
    int kb = (s*128 + i0)*16 + p;
    kps += hkv.x * kw2[kb];      qps += hqv.x * qw2[kb];
    kps += hkv.y * kw2[kb+16];   qps += hqv.y * qw2[kb+16];
    kps += hkv.z * kw2[kb+32];   qps += hqv.z * qw2[kb+32];
    kps += hkv.w * kw2[kb+48];   qps += hqv.w * qw2[kb+48];
  }
  kps += __shfl_xor(kps, 16); kps += __shfl_xor(kps, 32);
  qps += __shfl_xor(qps, 16); qps += __shfl_xor(qps, 32);
  const float PI = 3.14159265358979323846f;
  float kph = tanhf(kps + kb2[p]) * PI;
  float qph = tanhf(qps + qb2[p]) * PI;
  const float* hg = Hg + r*256;
  float4 hgv = *(const float4*)(hg + lane*4);
  float gp = hgv.x*gw2[lane*4] + hgv.y*gw2[lane*4+1]
           + hgv.z*gw2[lane*4+2] + hgv.w*gw2[lane*4+3];
  #pragma unroll
  for (int m = 1; m <= 32; m <<= 1) gp += __shfl_xor(gp, m);
  float gate = 1.f/(1.f + expf(-(gp + gb2[0])));
  float pph = (float)l * freqs[p] * 6.2831853071795864769f;
  float s0=setw[0], s1=setw[1], s2=setw[2], s3=setw[3];
  float mx = fmaxf(fmaxf(s0,s1), fmaxf(s2,s3));
  float e0=expf(s0-mx), e1=expf(s1-mx), e2=expf(s2-mx), e3=expf(s3-mx);
  float esum = e0+e1+e2+e3;
  int si = p >> 2;
  float wsel = (si==0? e0 : si==1? e1 : si==2? e2 : e3) / esum;
  float sigpw = 1.f/(1.f + expf(-posw[0]));
  float invnorm = rsqrtf((float)(l+1) * 4.0f);
  if (lane < 16) {
    float sk, ck, sq, cq, sp, cp;
    sincosf(kph, &sk, &ck);
    sincosf(qph, &sq, &cq);
    sincosf(pph, &sp, &cp);
    float* urow = ub + r*64;
    float* arow = ab + r*64;
    urow[p]      = ck;
    urow[16 + p] = sk;
    urow[32 + p] = cp;
    urow[48 + p] = sp;
    float ga = gate * wsel * invnorm;
    float pa = (1.f - gate) * sigpw * invnorm;
    arow[p]      = ga * cq;
    arow[16 + p] = ga * sq;
    arow[32 + p] = pa * cp;
    arow[48 + p] = pa * sp;
  }
}

// ---------------- scan pass A: per-chunk partial sums P[b][c][k][d] ----------------
__global__ __launch_bounds__(256) void k_scanA(const float* __restrict__ ub, const float* __restrict__ V,
                        float* __restrict__ P) {
  __shared__ float ul[CLEN][64];
  __shared__ float vl[CLEN][64];
  int t = threadIdx.x;
  int d0 = blockIdx.x*64; int c = blockIdx.y; int b = blockIdx.z;
  int srow = t >> 2, scol = (t & 3)*16;
  {
    const float* up = ub + (b*1024 + c*CLEN + srow)*64 + scol;
    *(float4*)&ul[srow][scol]    = *(const float4*)up;
    *(float4*)&ul[srow][scol+4]  = *(const float4*)(up+4);
    *(float4*)&ul[srow][scol+8]  = *(const float4*)(up+8);
    *(float4*)&ul[srow][scol+12] = *(const float4*)(up+12);
    const float* vp = V + (b*1024 + c*CLEN + srow)*512 + d0 + scol;
    *(float4*)&vl[srow][scol]    = *(const float4*)vp;
    *(float4*)&vl[srow][scol+4]  = *(const float4*)(vp+4);
    *(float4*)&vl[srow][scol+8]  = *(const float4*)(vp+8);
    *(float4*)&vl[srow][scol+12] = *(const float4*)(vp+12);
  }
  __syncthreads();
  int dd = t & 63, kg = t >> 6;
  float acc[16];
  #pragma unroll
  for (int i=0;i<16;i++) acc[i]=0.f;
  for (int tt = 0; tt < CLEN; tt++) {
    float vv = vl[tt][dd];
    #pragma unroll
    for (int i=0;i<16;i++) acc[i] += ul[tt][kg*16+i]*vv;
  }
  float* pp = P + (((b*NCH + c)*64) + kg*16)*512 + d0 + dd;
  #pragma unroll
  for (int i=0;i<16;i++) pp[i*512] = acc[i];
}

// ---------------- scan pass B: in-place exclusive prefix over chunks ----------------
__global__ __launch_bounds__(256) void k_scanB(float* __restrict__ P) {
  int tid = blockIdx.x*256 + threadIdx.x;   // 0..65535 = B*64*512
  int b = tid >> 15;
  int k = (tid >> 9) & 63;
  int d = tid & 511;
  float run = 0.f;
  float* base = P + ((b*NCH)*64 + k)*512 + d;
  for (int c = 0; c < NCH; c++) {
    float v = base[c*64*512];
    base[c*64*512] = run;
    run += v;
  }
}

// ---------------- scan pass C: intra-chunk sweep, 4 lanes per d, s[16] in regs ----------------
__global__ __launch_bounds__(256) void k_scanC(const float* __restrict__ ub, const float* __restrict__ ab,
                        const float* __restrict__ V, const float* __restrict__ P,
                        float* __restrict__ h) {
  __shared__ float ul[CLEN][64];
  __shared__ float al[CLEN][64];
  int t = threadIdx.x;
  int c = blockIdx.y; int b = blockIdx.z;
  int srow = t >> 2, scol = (t & 3)*16;
  {
    const float* up = ub + (b*1024 + c*CLEN + srow)*64 + scol;
    *(float4*)&ul[srow][scol]    = *(const float4*)up;
    *(float4*)&ul[srow][scol+4]  = *(const float4*)(up+4);
    *(float4*)&ul[srow][scol+8]  = *(const float4*)(up+8);
    *(float4*)&ul[srow][scol+12] = *(const float4*)(up+12);
    const float* ap = ab + (b*1024 + c*CLEN + srow)*64 + scol;
    *(float4*)&al[srow][scol]    = *(const float4*)ap;
    *(float4*)&al[srow][scol+4]  = *(const float4*)(ap+4);
    *(float4*)&al[srow][scol+8]  = *(const float4*)(ap+8);
    *(float4*)&al[srow][scol+12] = *(const float4*)(ap+12);
  }
  __syncthreads();
  int kg = t & 3;          // 4 lanes share one d; each owns 16 features
  int di = t >> 2;         // 0..63
  int d = blockIdx.x*64 + di;
  float s[16];
  const float* pb = P + ((b*NCH + c)*64 + kg*16)*512 + d;
  #pragma unroll
  for (int k = 0; k < 16; k++) s[k] = pb[k*512];
  const float* vrow = V + (b*1024 + c*CLEN)*512 + d;
  float* hrow = h + (b*1024 + c*CLEN)*512 + d;
  const float4* ul4 = (const float4*)&ul[0][0];
  const float4* al4 = (const float4*)&al[0][0];
  for (int tt = 0; tt < CLEN; tt++) {
    float vv = vrow[tt*512];
    float4 u0 = ul4[tt*16 + kg*4 + 0];
    float4 u1 = ul4[tt*16 + kg*4 + 1];
    float4 u2 = ul4[tt*16 + kg*4 + 2];
    float4 u3 = ul4[tt*16 + kg*4 + 3];
    float4 a0 = al4[tt*16 + kg*4 + 0];
    float4 a1 = al4[tt*16 + kg*4 + 1];
    float4 a2 = al4[tt*16 + kg*4 + 2];
    float4 a3 = al4[tt*16 + kg*4 + 3];
    float h0=0.f, h1=0.f, h2=0.f, h3=0.f;
    s[0]  += u0.x*vv; h0 += a0.x*s[0];
    s[1]  += u0.y*vv; h1 += a0.y*s[1];
    s[2]  += u0.z*vv; h2 += a0.z*s[2];
    s[3]  += u0.w*vv; h3 += a0.w*s[3];
    s[4]  += u1.x*vv; h0 += a1.x*s[4];
    s[5]  += u1.y*vv; h1 += a1.y*s[5];
    s[6]  += u1.z*vv; h2 += a1.z*s[6];
    s[7]  += u1.w*vv; h3 += a1.w*s[7];
    s[8]  += u2.x*vv; h0 += a2.x*s[8];
    s[9]  += u2.y*vv; h1 += a2.y*s[9];
    s[10] += u2.z*vv; h2 += a2.z*s[10];
    s[11] += u2.w*vv; h3 += a2.w*s[11];
    s[12] += u3.x*vv; h0 += a3.x*s[12];
    s[13] += u3.y*vv; h1 += a3.y*s[13];
    s[14] += u3.z*vv; h2 += a3.z*s[14];
    s[15] += u3.w*vv; h3 += a3.w*s[15];
    float hp = (h0+h1)+(h2+h3);
    hp += __shfl_xor(hp, 1);
    hp += __shfl_xor(hp, 2);
    if (kg == 0) hrow[tt*512] = hp;
  }
}

// ---------------- layernorm: one wave per row, bf16 out ----------------
__global__ __launch_bounds__(256) void k_ln(const float* __restrict__ h, const float* __restrict__ g,
                     const float* __restrict__ bta, u16* __restrict__ hln) {
  int t = threadIdx.x;
  int wid = t >> 6, lane = t & 63;
  int r = blockIdx.x*4 + wid;
  const float* hr = h + r*512;
  float4 v0 = *(const float4*)(hr + lane*8);
  float4 v1 = *(const float4*)(hr + lane*8 + 4);
  float vals[8] = {v0.x,v0.y,v0.z,v0.w,v1.x,v1.y,v1.z,v1.w};
  float sum = 0.f, sq = 0.f;
  #pragma unroll
  for (int i=0;i<8;i++){ sum += vals[i]; sq += vals[i]*vals[i]; }
  #pragma unroll
  for (int m = 1; m <= 32; m <<= 1){ sum += __shfl_xor(sum, m); sq += __shfl_xor(sq, m); }
  float mu = sum * (1.f/512.f);
  float var = sq * (1.f/512.f) - mu*mu;
  float rstd = rsqrtf(var + 1e-5f);
  unsigned o[4];
  #pragma unroll
  for (int i=0;i<4;i++){
    u16 lo = f2b((vals[2*i]  -mu)*rstd*g[lane*8+2*i]   + bta[lane*8+2*i]);
    u16 hi = f2b((vals[2*i+1]-mu)*rstd*g[lane*8+2*i+1] + bta[lane*8+2*i+1]);
    o[i] = (unsigned)lo | ((unsigned)hi << 16);
  }
  uint4 ov = make_uint4(o[0],o[1],o[2],o[3]);
  *(uint4*)(hln + r*512 + lane*8) = ov;
}

extern "C" void kernel_launch(void* const* d_in, const int* in_sizes, int n_in,
                              void* d_out, int out_size, void* d_ws, size_t ws_size,
                              hipStream_t stream) {
  const float* x       = (const float*)d_in[0];
  const float* ke_w1   = (const float*)d_in[1];
  const float* ke_b1   = (const float*)d_in[2];
  const float* ke_w2   = (const float*)d_in[3];
  const float* ke_b2   = (const float*)d_in[4];
  const float* qe_w1   = (const float*)d_in[5];
  const float* qe_b1   = (const float*)d_in[6];
  const float* qe_w2   = (const float*)d_in[7];
  const float* qe_b2   = (const float*)d_in[8];
  const float* v_w     = (const float*)d_in[9];
  const float* v_b     = (const float*)d_in[10];
  const float* ln_g    = (const float*)d_in[11];
  const float* ln_b    = (const float*)d_in[12];
  const float* out_w   = (const float*)d_in[13];
  const float* out_b   = (const float*)d_in[14];
  const float* setw    = (const float*)d_in[15];
  const float* posw    = (const float*)d_in[16];
  const float* gate_w1 = (const float*)d_in[17];
  const float* gate_b1 = (const float*)d_in[18];
  const float* gate_w2 = (const float*)d_in[19];
  const float* gate_b2 = (const float*)d_in[20];
  const float* freqs   = (const float*)d_in[21];
  float* out = (float*)d_out;

  char* ws = (char*)d_ws;
  u16*   xb  = (u16*)(ws + 0);            // 2048x512 bf16 (2 MB)
  u16*   BTF = (u16*)(ws + 2097152);      // 1792x512 bf16 (1.75 MB)
  u16*   oT  = (u16*)(ws + 3932160);      // 512x512 bf16 (512 KB)
  float* Hke = (float*)(ws + 4456448);    // 2048x512 f32 (reused as h)
  float* Hqe = (float*)(ws + 8650752);    // 2048x512 f32 (reused as hln bf16)
  float* Hg  = (float*)(ws + 12845056);   // 2048x256 f32
  float* V   = (float*)(ws + 14942208);   // 2048x512 f32
  float* ubf = (float*)(ws + 19136512);   // 2048x64 f32
  float* abf = (float*)(ws + 19660800);   // 2048x64 f32
  float* P   = (float*)(ws + 20185088);   // 2*16*64*512 f32 = 4 MB (ends 24379392)
  float* h   = Hke;                       // overlay (Hke consumed by k_phase)
  u16*   hln = (u16*)Hqe;                 // overlay (Hqe consumed by k_phase)

  u16* keT = BTF;                // rows 0..511
  u16* qeT = BTF + 512*512;      // rows 512..1023
  u16* vT  = BTF + 1024*512;     // rows 1024..1535
  u16* gT  = BTF + 1536*512;     // rows 1536..1791

  k_prep<<<512 + 5*256, 256, 0, stream>>>(x, xb, ke_w1,qe_w1,v_w,gate_w1,out_w,
                                          keT,qeT,vT,gT,oT);
  k_gemm4<<<dim3(14,16),256,0,stream>>>(xb, BTF, ke_b1, qe_b1, v_b, gate_b1,
                                        Hke, Hqe, V, Hg);
  k_phase<<<512,256,0,stream>>>(Hke,Hqe,Hg, ke_w2,ke_b2, qe_w2,qe_b2,
                                gate_w2,gate_b2, setw,posw,freqs, ubf,abf);
  k_scanA<<<dim3(8,NCH,2),256,0,stream>>>(ubf, V, P);
  k_scanB<<<256,256,0,stream>>>(P);
  k_scanC<<<dim3(8,NCH,2),256,0,stream>>>(ubf, abf, V, P, h);
  k_ln<<<512,256,0,stream>>>(h, ln_g, ln_b, hln);
  k_gemm_out<<<dim3(4,16),256,0,stream>>>(hln, oT, out_b, x, out);
}

// Round 6
// 92.673 us; speedup vs baseline: 1.1017x; 1.1017x over previous
//
#include <hip/hip_runtime.h>

typedef unsigned short u16;
typedef __attribute__((ext_vector_type(8))) __bf16 bf16x8;
typedef __attribute__((ext_vector_type(4))) float f32x4;

#define DI __device__ __forceinline__

DI u16 f2b(float f){ union{float f; unsigned u;} x; x.f = f; unsigned u = x.u;
  return (u16)((u + 0x7FFFu + ((u>>16)&1u)) >> 16); }

#define NCH 16   // number of chunks
#define CLEN 64  // chunk length  (NCH*CLEN == L == 1024)

// ---------------- prep: cast x->bf16 (blocks 0..511) + 5 weight transposes ----------------
__global__ __launch_bounds__(256) void k_prep(const float* __restrict__ x, u16* __restrict__ xb,
                            const float* w0, const float* w1, const float* w2, const float* w3, const float* w4,
                            u16* t0, u16* t1, u16* t2, u16* t3, u16* t4) {
  __shared__ u16 tile[32][33];
  int z = blockIdx.x;
  int t = threadIdx.x;
  if (z < 512) {
    int i = (z*256 + t)*8;
    float4 a = *(const float4*)(x+i);
    float4 b = *(const float4*)(x+i+4);
    unsigned o0 = (unsigned)f2b(a.x) | ((unsigned)f2b(a.y)<<16);
    unsigned o1 = (unsigned)f2b(a.z) | ((unsigned)f2b(a.w)<<16);
    unsigned o2 = (unsigned)f2b(b.x) | ((unsigned)f2b(b.y)<<16);
    unsigned o3 = (unsigned)f2b(b.z) | ((unsigned)f2b(b.w)<<16);
    *(uint4*)(xb+i) = make_uint4(o0,o1,o2,o3);
    return;
  }
  z -= 512;
  int which = z >> 8;       // 0..4
  int rem = z & 255;
  const float* src; u16* dst; int K, N;
  if (which==0){src=w0;dst=t0;K=512;N=512;}
  else if(which==1){src=w1;dst=t1;K=512;N=512;}
  else if(which==2){src=w2;dst=t2;K=512;N=512;}
  else if(which==3){src=w3;dst=t3;K=512;N=256;}
  else             {src=w4;dst=t4;K=512;N=512;}
  int n0 = (rem & 15)*32, k0 = (rem >> 4)*32;
  if (n0 >= N) return;
  int tx = t & 31, ty = t >> 5; // 32 x 8
  #pragma unroll
  for (int r = 0; r < 4; r++) tile[ty + 8*r][tx] = f2b(src[(k0 + ty + 8*r)*N + n0 + tx]);
  __syncthreads();
  #pragma unroll
  for (int r = 0; r < 4; r++) dst[(n0 + ty + 8*r)*K + k0 + tx] = tile[tx][ty + 8*r];
}

// ---------------- fused first-layer GEMM (64x64 tile, padded LDS) ----------------
// n ranges: [0,512) ke->GELU->Hke ; [512,1024) qe->GELU->Hqe ;
//           [1024,1536) v->plain->V ; [1536,1792) gate->GELU->Hg (stride 256)
__global__ __launch_bounds__(256) void k_gemm4(const u16* __restrict__ A, const u16* __restrict__ BTF,
                       const float* __restrict__ kb1, const float* __restrict__ qb1,
                       const float* __restrict__ vb,  const float* __restrict__ gbias1,
                       float* __restrict__ Hke, float* __restrict__ Hqe,
                       float* __restrict__ V,   float* __restrict__ Hg) {
  const int K = 512;
  __shared__ short As[64][48];
  __shared__ short Bs[64][48];
  int t = threadIdx.x;
  int bm = blockIdx.y*64, bn = blockIdx.x*64;
  int lane = t & 63, wid = t >> 6;
  int wm = (wid>>1)*32, wn = (wid&1)*32;
  int lr = lane & 15, ls = lane >> 4;
  f32x4 zero = {0.f,0.f,0.f,0.f};
  f32x4 acc[2][2];
  acc[0][0]=zero; acc[0][1]=zero; acc[1][0]=zero; acc[1][1]=zero;
  int srow = t >> 2, scol = (t & 3)*8;
  for (int k0 = 0; k0 < K; k0 += 32) {
    __syncthreads();
    *(bf16x8*)&As[srow][scol] = *(const bf16x8*)(A   + (bm+srow)*K + k0 + scol);
    *(bf16x8*)&Bs[srow][scol] = *(const bf16x8*)(BTF + (bn+srow)*K + k0 + scol);
    __syncthreads();
    bf16x8 a0 = *(const bf16x8*)&As[wm + lr][ls*8];
    bf16x8 a1 = *(const bf16x8*)&As[wm + 16 + lr][ls*8];
    bf16x8 b0 = *(const bf16x8*)&Bs[wn + lr][ls*8];
    bf16x8 b1 = *(const bf16x8*)&Bs[wn + 16 + lr][ls*8];
    acc[0][0] = __builtin_amdgcn_mfma_f32_16x16x32_bf16(a0, b0, acc[0][0], 0,0,0);
    acc[0][1] = __builtin_amdgcn_mfma_f32_16x16x32_bf16(a0, b1, acc[0][1], 0,0,0);
    acc[1][0] = __builtin_amdgcn_mfma_f32_16x16x32_bf16(a1, b0, acc[1][0], 0,0,0);
    acc[1][1] = __builtin_amdgcn_mfma_f32_16x16x32_bf16(a1, b1, acc[1][1], 0,0,0);
  }
  float* C; const float* bias; int nstr, nb; bool gel;
  if (bn < 512)       { C=Hke; bias=kb1;    nstr=512; nb=bn;      gel=true;  }
  else if (bn < 1024) { C=Hqe; bias=qb1;    nstr=512; nb=bn-512;  gel=true;  }
  else if (bn < 1536) { C=V;   bias=vb;     nstr=512; nb=bn-1024; gel=false; }
  else                { C=Hg;  bias=gbias1; nstr=256; nb=bn-1536; gel=true;  }
  #pragma unroll
  for (int fm = 0; fm < 2; fm++)
    #pragma unroll
    for (int fn = 0; fn < 2; fn++)
      #pragma unroll
      for (int r = 0; r < 4; r++) {
        int grow = bm + wm + fm*16 + ls*4 + r;
        int gcol = nb + wn + fn*16 + lr;
        float v = acc[fm][fn][r] + bias[gcol];
        if (gel) v = 0.5f*v*(1.0f + erff(v*0.70710678118654752f));
        C[grow*nstr + gcol] = v;
      }
}

// ---------------- fused LN + output GEMM: out = x + LN(h) @ oT + bias ----------------
__global__ __launch_bounds__(256) void k_gemm_out_ln(
                       const float* __restrict__ h,   const float* __restrict__ lng,
                       const float* __restrict__ lnb, const u16* __restrict__ BT,
                       const float* __restrict__ bias, const float* __restrict__ resid,
                       float* __restrict__ C) {
  const int K = 512;
  __shared__ short As[64][48];
  __shared__ short Bs[64][48];
  __shared__ float mu_s[64], rs_s[64];
  int t = threadIdx.x;
  int bm = blockIdx.y*64, bn = blockIdx.x*64;
  int lane = t & 63, wid = t >> 6;
  int wm = (wid>>1)*32, wn = (wid&1)*32;
  int lr = lane & 15, ls = lane >> 4;
  // ---- LN stats for this block's 64 A-rows (4 lanes per row) ----
  {
    int r = t >> 2, q = t & 3;
    const float* hr = h + (bm + r)*512 + q*128;
    float sum = 0.f, sq = 0.f;
    #pragma unroll 8
    for (int i = 0; i < 128; i += 4) {
      float4 v = *(const float4*)(hr + i);
      sum += (v.x+v.y)+(v.z+v.w);
      sq  += (v.x*v.x+v.y*v.y)+(v.z*v.z+v.w*v.w);
    }
    sum += __shfl_xor(sum,1); sum += __shfl_xor(sum,2);
    sq  += __shfl_xor(sq,1);  sq  += __shfl_xor(sq,2);
    if (q == 0) {
      float mu = sum * (1.f/512.f);
      float var = sq * (1.f/512.f) - mu*mu;
      mu_s[r] = mu;
      rs_s[r] = rsqrtf(var + 1e-5f);
    }
  }
  __syncthreads();
  f32x4 zero = {0.f,0.f,0.f,0.f};
  f32x4 acc[2][2];
  acc[0][0]=zero; acc[0][1]=zero; acc[1][0]=zero; acc[1][1]=zero;
  int srow = t >> 2, scol = (t & 3)*8;
  for (int k0 = 0; k0 < K; k0 += 32) {
    __syncthreads();
    // A-stage: LN(h) -> bf16 on the fly
    {
      const float* hp = h + (bm+srow)*512 + k0 + scol;
      float4 a  = *(const float4*)hp;
      float4 b  = *(const float4*)(hp+4);
      float4 g0 = *(const float4*)(lng + k0 + scol);
      float4 g1 = *(const float4*)(lng + k0 + scol + 4);
      float4 c0 = *(const float4*)(lnb + k0 + scol);
      float4 c1 = *(const float4*)(lnb + k0 + scol + 4);
      float mu = mu_s[srow], rs = rs_s[srow];
      unsigned o0 = (unsigned)f2b((a.x-mu)*rs*g0.x+c0.x) | ((unsigned)f2b((a.y-mu)*rs*g0.y+c0.y)<<16);
      unsigned o1 = (unsigned)f2b((a.z-mu)*rs*g0.z+c0.z) | ((unsigned)f2b((a.w-mu)*rs*g0.w+c0.w)<<16);
      unsigned o2 = (unsigned)f2b((b.x-mu)*rs*g1.x+c1.x) | ((unsigned)f2b((b.y-mu)*rs*g1.y+c1.y)<<16);
      unsigned o3 = (unsigned)f2b((b.z-mu)*rs*g1.z+c1.z) | ((unsigned)f2b((b.w-mu)*rs*g1.w+c1.w)<<16);
      *(uint4*)&As[srow][scol] = make_uint4(o0,o1,o2,o3);
    }
    *(bf16x8*)&Bs[srow][scol] = *(const bf16x8*)(BT + (bn+srow)*K + k0 + scol);
    __syncthreads();
    bf16x8 a0 = *(const bf16x8*)&As[wm + lr][ls*8];
    bf16x8 a1 = *(const bf16x8*)&As[wm + 16 + lr][ls*8];
    bf16x8 b0 = *(const bf16x8*)&Bs[wn + lr][ls*8];
    bf16x8 b1 = *(const bf16x8*)&Bs[wn + 16 + lr][ls*8];
    acc[0][0] = __builtin_amdgcn_mfma_f32_16x16x32_bf16(a0, b0, acc[0][0], 0,0,0);
    acc[0][1] = __builtin_amdgcn_mfma_f32_16x16x32_bf16(a0, b1, acc[0][1], 0,0,0);
    acc[1][0] = __builtin_amdgcn_mfma_f32_16x16x32_bf16(a1, b0, acc[1][0], 0,0,0);
    acc[1][1] = __builtin_amdgcn_mfma_f32_16x16x32_bf16(a1, b1, acc[1][1], 0,0,0);
  }
  #pragma unroll
  for (int fm = 0; fm < 2; fm++)
    #pragma unroll
    for (int fn = 0; fn < 2; fn++)
      #pragma unroll
      for (int r = 0; r < 4; r++) {
        int grow = bm + wm + fm*16 + ls*4 + r;
        int gcol = bn + wn + fn*16 + lr;
        float v = acc[fm][fn][r] + bias[gcol] + resid[grow*512 + gcol];
        C[grow*512 + gcol] = v;
      }
}

// ---------------- phases / features: one wave per row ----------------
__global__ __launch_bounds__(256) void k_phase(const float* __restrict__ Hke, const float* __restrict__ Hqe,
                        const float* __restrict__ Hg,
                        const float* __restrict__ kw2, const float* __restrict__ kb2,
                        const float* __restrict__ qw2, const float* __restrict__ qb2,
                        const float* __restrict__ gw2, const float* __restrict__ gb2,
                        const float* __restrict__ setw, const float* __restrict__ posw,
                        const float* __restrict__ freqs,
                        float* __restrict__ ub, float* __restrict__ ab) {
  int t = threadIdx.x;
  int wid = t >> 6, lane = t & 63;
  int r = blockIdx.x*4 + wid;
  int l = r & 1023;
  int p = lane & 15, s = lane >> 4;
  const float* hk = Hke + r*512 + s*128;
  const float* hq = Hqe + r*512 + s*128;
  float kps = 0.f, qps = 0.f;
  for (int i0 = 0; i0 < 128; i0 += 4) {
    float4 hkv = *(const float4*)(hk + i0);
    float4 hqv = *(const float4*)(hq + i0);
    int kb = (s*128 + i0)*16 + p;
    kps += hkv.x * kw2[kb];      qps += hqv.x * qw2[kb];
    kps += hkv.y * kw2[kb+16];   qps += hqv.y * qw2[kb+16];
    kps += hkv.z * kw2[kb+32];   qps += hqv.z * qw2[kb+32];
    kps += hkv.w * kw2[kb+48];   qps += hqv.w * qw2[kb+48];
  }
  kps += __shfl_xor(kps, 16); kps += __shfl_xor(kps, 32);
  qps += __shfl_xor(qps, 16); qps += __shfl_xor(qps, 32);
  const float PI = 3.14159265358979323846f;
  float kph = tanhf(kps + kb2[p]) * PI;
  float qph = tanhf(qps + qb2[p]) * PI;
  const float* hg = Hg + r*256;
  float4 hgv = *(const float4*)(hg + lane*4);
  float gp = hgv.x*gw2[lane*4] + hgv.y*gw2[lane*4+1]
           + hgv.z*gw2[lane*4+2] + hgv.w*gw2[lane*4+3];
  #pragma unroll
  for (int m = 1; m <= 32; m <<= 1) gp += __shfl_xor(gp, m);
  float gate = 1.f/(1.f + expf(-(gp + gb2[0])));
  float pph = (float)l * freqs[p] * 6.2831853071795864769f;
  float s0=setw[0], s1=setw[1], s2=setw[2], s3=setw[3];
  float mx = fmaxf(fmaxf(s0,s1), fmaxf(s2,s3));
  float e0=expf(s0-mx), e1=expf(s1-mx), e2=expf(s2-mx), e3=expf(s3-mx);
  float esum = e0+e1+e2+e3;
  int si = p >> 2;
  float wsel = (si==0? e0 : si==1? e1 : si==2? e2 : e3) / esum;
  float sigpw = 1.f/(1.f + expf(-posw[0]));
  float invnorm = rsqrtf((float)(l+1) * 4.0f);
  if (lane < 16) {
    float sk, ck, sq, cq, sp, cp;
    sincosf(kph, &sk, &ck);
    sincosf(qph, &sq, &cq);
    sincosf(pph, &sp, &cp);
    float* urow = ub + r*64;
    float* arow = ab + r*64;
    urow[p]      = ck;
    urow[16 + p] = sk;
    urow[32 + p] = cp;
    urow[48 + p] = sp;
    float ga = gate * wsel * invnorm;
    float pa = (1.f - gate) * sigpw * invnorm;
    arow[p]      = ga * cq;
    arow[16 + p] = ga * sq;
    arow[32 + p] = pa * cp;
    arow[48 + p] = pa * sp;
  }
}

// ---------------- scan pass A: per-chunk partial sums P[b][c][k][d] ----------------
__global__ __launch_bounds__(256) void k_scanA(const float* __restrict__ ub, const float* __restrict__ V,
                        float* __restrict__ P) {
  __shared__ float ul[CLEN][64];
  __shared__ float vl[CLEN][64];
  int t = threadIdx.x;
  int d0 = blockIdx.x*64; int c = blockIdx.y; int b = blockIdx.z;
  int srow = t >> 2, scol = (t & 3)*16;
  {
    const float* up = ub + (b*1024 + c*CLEN + srow)*64 + scol;
    *(float4*)&ul[srow][scol]    = *(const float4*)up;
    *(float4*)&ul[srow][scol+4]  = *(const float4*)(up+4);
    *(float4*)&ul[srow][scol+8]  = *(const float4*)(up+8);
    *(float4*)&ul[srow][scol+12] = *(const float4*)(up+12);
    const float* vp = V + (b*1024 + c*CLEN + srow)*512 + d0 + scol;
    *(float4*)&vl[srow][scol]    = *(const float4*)vp;
    *(float4*)&vl[srow][scol+4]  = *(const float4*)(vp+4);
    *(float4*)&vl[srow][scol+8]  = *(const float4*)(vp+8);
    *(float4*)&vl[srow][scol+12] = *(const float4*)(vp+12);
  }
  __syncthreads();
  int dd = t & 63, kg = t >> 6;
  float acc[16];
  #pragma unroll
  for (int i=0;i<16;i++) acc[i]=0.f;
  for (int tt = 0; tt < CLEN; tt++) {
    float vv = vl[tt][dd];
    #pragma unroll
    for (int i=0;i<16;i++) acc[i] += ul[tt][kg*16+i]*vv;
  }
  float* pp = P + (((b*NCH + c)*64) + kg*16)*512 + d0 + dd;
  #pragma unroll
  for (int i=0;i<16;i++) pp[i*512] = acc[i];
}

// ---------------- scan pass BC: exclusive chunk-prefix (from L2) + intra-chunk sweep ----------------
__global__ __launch_bounds__(256) void k_scanBC(const float* __restrict__ ub, const float* __restrict__ ab,
                        const float* __restrict__ V, const float* __restrict__ P,
                        float* __restrict__ h) {
  __shared__ float ul[CLEN][64];
  __shared__ float al[CLEN][64];
  int t = threadIdx.x;
  int c = blockIdx.y; int b = blockIdx.z;
  int srow = t >> 2, scol = (t & 3)*16;
  {
    const float* up = ub + (b*1024 + c*CLEN + srow)*64 + scol;
    *(float4*)&ul[srow][scol]    = *(const float4*)up;
    *(float4*)&ul[srow][scol+4]  = *(const float4*)(up+4);
    *(float4*)&ul[srow][scol+8]  = *(const float4*)(up+8);
    *(float4*)&ul[srow][scol+12] = *(const float4*)(up+12);
    const float* ap = ab + (b*1024 + c*CLEN + srow)*64 + scol;
    *(float4*)&al[srow][scol]    = *(const float4*)ap;
    *(float4*)&al[srow][scol+4]  = *(const float4*)(ap+4);
    *(float4*)&al[srow][scol+8]  = *(const float4*)(ap+8);
    *(float4*)&al[srow][scol+12] = *(const float4*)(ap+12);
  }
  __syncthreads();
  int kg = t & 3;          // 4 lanes share one d; each owns 16 features
  int di = t >> 2;         // 0..63
  int d = blockIdx.x*64 + di;
  float s[16];
  #pragma unroll
  for (int k = 0; k < 16; k++) s[k] = 0.f;
  // exclusive prefix over chunks, read straight from P (L2-resident)
  const float* pb = P + ((b*NCH)*64 + kg*16)*512 + d;
  for (int cc = 0; cc < c; cc++) {
    #pragma unroll
    for (int k = 0; k < 16; k++) s[k] += pb[(cc*64 + k)*512];
  }
  const float* vrow = V + (b*1024 + c*CLEN)*512 + d;
  float* hrow = h + (b*1024 + c*CLEN)*512 + d;
  const float4* ul4 = (const float4*)&ul[0][0];
  const float4* al4 = (const float4*)&al[0][0];
  for (int tt = 0; tt < CLEN; tt++) {
    float vv = vrow[tt*512];
    float4 u0 = ul4[tt*16 + kg*4 + 0];
    float4 u1 = ul4[tt*16 + kg*4 + 1];
    float4 u2 = ul4[tt*16 + kg*4 + 2];
    float4 u3 = ul4[tt*16 + kg*4 + 3];
    float4 a0 = al4[tt*16 + kg*4 + 0];
    float4 a1 = al4[tt*16 + kg*4 + 1];
    float4 a2 = al4[tt*16 + kg*4 + 2];
    float4 a3 = al4[tt*16 + kg*4 + 3];
    float h0=0.f, h1=0.f, h2=0.f, h3=0.f;
    s[0]  += u0.x*vv; h0 += a0.x*s[0];
    s[1]  += u0.y*vv; h1 += a0.y*s[1];
    s[2]  += u0.z*vv; h2 += a0.z*s[2];
    s[3]  += u0.w*vv; h3 += a0.w*s[3];
    s[4]  += u1.x*vv; h0 += a1.x*s[4];
    s[5]  += u1.y*vv; h1 += a1.y*s[5];
    s[6]  += u1.z*vv; h2 += a1.z*s[6];
    s[7]  += u1.w*vv; h3 += a1.w*s[7];
    s[8]  += u2.x*vv; h0 += a2.x*s[8];
    s[9]  += u2.y*vv; h1 += a2.y*s[9];
    s[10] += u2.z*vv; h2 += a2.z*s[10];
    s[11] += u2.w*vv; h3 += a2.w*s[11];
    s[12] += u3.x*vv; h0 += a3.x*s[12];
    s[13] += u3.y*vv; h1 += a3.y*s[13];
    s[14] += u3.z*vv; h2 += a3.z*s[14];
    s[15] += u3.w*vv; h3 += a3.w*s[15];
    float hp = (h0+h1)+(h2+h3);
    hp += __shfl_xor(hp, 1);
    hp += __shfl_xor(hp, 2);
    if (kg == 0) hrow[tt*512] = hp;
  }
}

extern "C" void kernel_launch(void* const* d_in, const int* in_sizes, int n_in,
                              void* d_out, int out_size, void* d_ws, size_t ws_size,
                              hipStream_t stream) {
  const float* x       = (const float*)d_in[0];
  const float* ke_w1   = (const float*)d_in[1];
  const float* ke_b1   = (const float*)d_in[2];
  const float* ke_w2   = (const float*)d_in[3];
  const float* ke_b2   = (const float*)d_in[4];
  const float* qe_w1   = (const float*)d_in[5];
  const float* qe_b1   = (const float*)d_in[6];
  const float* qe_w2   = (const float*)d_in[7];
  const float* qe_b2   = (const float*)d_in[8];
  const float* v_w     = (const float*)d_in[9];
  const float* v_b     = (const float*)d_in[10];
  const float* ln_g    = (const float*)d_in[11];
  const float* ln_b    = (const float*)d_in[12];
  const float* out_w   = (const float*)d_in[13];
  const float* out_b   = (const float*)d_in[14];
  const float* setw    = (const float*)d_in[15];
  const float* posw    = (const float*)d_in[16];
  const float* gate_w1 = (const float*)d_in[17];
  const float* gate_b1 = (const float*)d_in[18];
  const float* gate_w2 = (const float*)d_in[19];
  const float* gate_b2 = (const float*)d_in[20];
  const float* freqs   = (const float*)d_in[21];
  float* out = (float*)d_out;

  char* ws = (char*)d_ws;
  u16*   xb  = (u16*)(ws + 0);            // 2048x512 bf16 (2 MB)
  u16*   BTF = (u16*)(ws + 2097152);      // 1792x512 bf16 (1.75 MB)
  u16*   oT  = (u16*)(ws + 3932160);      // 512x512 bf16 (512 KB)
  float* Hke = (float*)(ws + 4456448);    // 2048x512 f32 (reused as h)
  float* Hqe = (float*)(ws + 8650752);    // 2048x512 f32
  float* Hg  = (float*)(ws + 12845056);   // 2048x256 f32
  float* V   = (float*)(ws + 14942208);   // 2048x512 f32
  float* ubf = (float*)(ws + 19136512);   // 2048x64 f32
  float* abf = (float*)(ws + 19660800);   // 2048x64 f32
  float* P   = (float*)(ws + 20185088);   // 2*16*64*512 f32 = 4 MB (ends 24379392)
  float* h   = Hke;                       // overlay (Hke consumed by k_phase)

  u16* keT = BTF;                // rows 0..511
  u16* qeT = BTF + 512*512;      // rows 512..1023
  u16* vT  = BTF + 1024*512;     // rows 1024..1535
  u16* gT  = BTF + 1536*512;     // rows 1536..1791

  k_prep<<<512 + 5*256, 256, 0, stream>>>(x, xb, ke_w1,qe_w1,v_w,gate_w1,out_w,
                                          keT,qeT,vT,gT,oT);
  k_gemm4<<<dim3(28,32),256,0,stream>>>(xb, BTF, ke_b1, qe_b1, v_b, gate_b1,
                                        Hke, Hqe, V, Hg);
  k_phase<<<512,256,0,stream>>>(Hke,Hqe,Hg, ke_w2,ke_b2, qe_w2,qe_b2,
                                gate_w2,gate_b2, setw,posw,freqs, ubf,abf);
  k_scanA<<<dim3(8,NCH,2),256,0,stream>>>(ubf, V, P);
  k_scanBC<<<dim3(8,NCH,2),256,0,stream>>>(ubf, abf, V, P, h);
  k_gemm_out_ln<<<dim3(8,32),256,0,stream>>>(h, ln_g, ln_b, oT, out_b, x, out);
}

// Round 7
// 78.602 us; speedup vs baseline: 1.2989x; 1.1790x over previous
//
#include <hip/hip_runtime.h>

typedef unsigned short u16;
typedef __attribute__((ext_vector_type(8))) __bf16 bf16x8;
typedef __attribute__((ext_vector_type(4))) float f32x4;

#define DI __device__ __forceinline__

DI u16 f2b(float f){ union{float f; unsigned u;} x; x.f = f; unsigned u = x.u;
  return (u16)((u + 0x7FFFu + ((u>>16)&1u)) >> 16); }

#define NCH 16   // number of chunks
#define CLEN 64  // chunk length  (NCH*CLEN == L == 1024)

// ---------------- prep: cast x->bf16 (blocks 0..511) + 5 weight transposes ----------------
__global__ __launch_bounds__(256) void k_prep(const float* __restrict__ x, u16* __restrict__ xb,
                            const float* w0, const float* w1, const float* w2, const float* w3, const float* w4,
                            u16* t0, u16* t1, u16* t2, u16* t3, u16* t4) {
  __shared__ u16 tile[32][33];
  int z = blockIdx.x;
  int t = threadIdx.x;
  if (z < 512) {
    int i = (z*256 + t)*8;
    float4 a = *(const float4*)(x+i);
    float4 b = *(const float4*)(x+i+4);
    unsigned o0 = (unsigned)f2b(a.x) | ((unsigned)f2b(a.y)<<16);
    unsigned o1 = (unsigned)f2b(a.z) | ((unsigned)f2b(a.w)<<16);
    unsigned o2 = (unsigned)f2b(b.x) | ((unsigned)f2b(b.y)<<16);
    unsigned o3 = (unsigned)f2b(b.z) | ((unsigned)f2b(b.w)<<16);
    *(uint4*)(xb+i) = make_uint4(o0,o1,o2,o3);
    return;
  }
  z -= 512;
  int which = z >> 8;       // 0..4
  int rem = z & 255;
  const float* src; u16* dst; int K, N;
  if (which==0){src=w0;dst=t0;K=512;N=512;}
  else if(which==1){src=w1;dst=t1;K=512;N=512;}
  else if(which==2){src=w2;dst=t2;K=512;N=512;}
  else if(which==3){src=w3;dst=t3;K=512;N=256;}
  else             {src=w4;dst=t4;K=512;N=512;}
  int n0 = (rem & 15)*32, k0 = (rem >> 4)*32;
  if (n0 >= N) return;
  int tx = t & 31, ty = t >> 5; // 32 x 8
  #pragma unroll
  for (int r = 0; r < 4; r++) tile[ty + 8*r][tx] = f2b(src[(k0 + ty + 8*r)*N + n0 + tx]);
  __syncthreads();
  #pragma unroll
  for (int r = 0; r < 4; r++) dst[(n0 + ty + 8*r)*K + k0 + tx] = tile[tx][ty + 8*r];
}

// ============ 64x64-tile MFMA mainloop, BK=64, dbuf LDS, 2-step-ahead prefetch ============
// A, BT bf16 row-major K=512. 4 waves x 32x32 output each (acc[2][2]).
// One __syncthreads per K-step (8 steps). Padded LDS [64][72] (conflict-free).
#define GEMM64_LOOP(APTR, BPTR)                                                       \
  __shared__ short As[2][64][72];                                                     \
  __shared__ short Bs[2][64][72];                                                     \
  int t = threadIdx.x;                                                                \
  int lane = t & 63, wid = t >> 6;                                                    \
  int wm = (wid>>1)*32, wn = (wid&1)*32;                                              \
  int lr = lane & 15, ls = lane >> 4;                                                 \
  int srow = t >> 2, scol = (t & 3)*16;                                               \
  f32x4 acc[2][2];                                                                    \
  { f32x4 z_={0.f,0.f,0.f,0.f}; acc[0][0]=z_;acc[0][1]=z_;acc[1][0]=z_;acc[1][1]=z_; }\
  const u16* gA = (APTR) + (bm+srow)*512 + scol;                                      \
  const u16* gB = (BPTR) + (bn+srow)*512 + scol;                                      \
  bf16x8 rA0 = *(const bf16x8*)(gA);      bf16x8 rA1 = *(const bf16x8*)(gA+8);        \
  bf16x8 rB0 = *(const bf16x8*)(gB);      bf16x8 rB1 = *(const bf16x8*)(gB+8);        \
  bf16x8 nA0 = *(const bf16x8*)(gA+64);   bf16x8 nA1 = *(const bf16x8*)(gA+72);       \
  bf16x8 nB0 = *(const bf16x8*)(gB+64);   bf16x8 nB1 = *(const bf16x8*)(gB+72);       \
  *(bf16x8*)&As[0][srow][scol] = rA0; *(bf16x8*)&As[0][srow][scol+8] = rA1;           \
  *(bf16x8*)&Bs[0][srow][scol] = rB0; *(bf16x8*)&Bs[0][srow][scol+8] = rB1;           \
  __syncthreads();                                                                    \
  _Pragma("unroll")                                                                   \
  for (int st = 0; st < 8; st++) {                                                    \
    int cur = st & 1;                                                                 \
    bf16x8 af_[2][2], bf_[2][2];                                                      \
    _Pragma("unroll")                                                                 \
    for (int ks = 0; ks < 2; ks++) {                                                  \
      _Pragma("unroll")                                                               \
      for (int mi = 0; mi < 2; mi++) {                                                \
        af_[mi][ks] = *(const bf16x8*)&As[cur][wm+mi*16+lr][ks*32+ls*8];              \
        bf_[mi][ks] = *(const bf16x8*)&Bs[cur][wn+mi*16+lr][ks*32+ls*8];              \
      }                                                                               \
    }                                                                                 \
    if (st < 7) {                                                                     \
      *(bf16x8*)&As[cur^1][srow][scol] = nA0; *(bf16x8*)&As[cur^1][srow][scol+8] = nA1; \
      *(bf16x8*)&Bs[cur^1][srow][scol] = nB0; *(bf16x8*)&Bs[cur^1][srow][scol+8] = nB1; \
    }                                                                                 \
    if (st < 6) {                                                                     \
      int kk = (st+2)*64;                                                             \
      nA0 = *(const bf16x8*)(gA+kk);    nA1 = *(const bf16x8*)(gA+kk+8);              \
      nB0 = *(const bf16x8*)(gB+kk);    nB1 = *(const bf16x8*)(gB+kk+8);              \
    }                                                                                 \
    _Pragma("unroll")                                                                 \
    for (int ks = 0; ks < 2; ks++)                                                    \
      _Pragma("unroll")                                                               \
      for (int mi = 0; mi < 2; mi++)                                                  \
        _Pragma("unroll")                                                             \
        for (int ni = 0; ni < 2; ni++)                                                \
          acc[mi][ni] = __builtin_amdgcn_mfma_f32_16x16x32_bf16(af_[mi][ks], bf_[ni][ks], acc[mi][ni], 0,0,0); \
    __syncthreads();                                                                  \
  }

// ---------------- fused first-layer GEMM over concatenated BT [1792][512] ----------------
// n ranges: [0,512) ke->GELU->Hke ; [512,1024) qe->GELU->Hqe ;
//           [1024,1536) v->plain->V ; [1536,1792) gate->GELU->Hg (stride 256)
__global__ __launch_bounds__(256) void k_gemm4(const u16* __restrict__ A, const u16* __restrict__ BTF,
                       const float* __restrict__ kb1, const float* __restrict__ qb1,
                       const float* __restrict__ vb,  const float* __restrict__ gbias1,
                       float* __restrict__ Hke, float* __restrict__ Hqe,
                       float* __restrict__ V,   float* __restrict__ Hg) {
  int bm = blockIdx.y*64, bn = blockIdx.x*64;
  GEMM64_LOOP(A, BTF)
  float* C; const float* bias; int nstr, nb; bool gel;
  if (bn < 512)       { C=Hke; bias=kb1;    nstr=512; nb=bn;      gel=true;  }
  else if (bn < 1024) { C=Hqe; bias=qb1;    nstr=512; nb=bn-512;  gel=true;  }
  else if (bn < 1536) { C=V;   bias=vb;     nstr=512; nb=bn-1024; gel=false; }
  else                { C=Hg;  bias=gbias1; nstr=256; nb=bn-1536; gel=true;  }
  #pragma unroll
  for (int mi = 0; mi < 2; mi++)
    #pragma unroll
    for (int ni = 0; ni < 2; ni++)
      #pragma unroll
      for (int r = 0; r < 4; r++) {
        int grow = bm + wm + mi*16 + ls*4 + r;
        int gcol = nb + wn + ni*16 + lr;
        float v = acc[mi][ni][r] + bias[gcol];
        if (gel) v = 0.5f*v*(1.0f + erff(v*0.70710678118654752f));
        C[grow*nstr + gcol] = v;
      }
}

// ---------------- final GEMM: out = resid + hln @ oT + bias ----------------
__global__ __launch_bounds__(256) void k_gemm_out(const u16* __restrict__ A, const u16* __restrict__ BT,
                       const float* __restrict__ bias, const float* __restrict__ resid,
                       float* __restrict__ C) {
  int bm = blockIdx.y*64, bn = blockIdx.x*64;
  GEMM64_LOOP(A, BT)
  #pragma unroll
  for (int mi = 0; mi < 2; mi++)
    #pragma unroll
    for (int ni = 0; ni < 2; ni++)
      #pragma unroll
      for (int r = 0; r < 4; r++) {
        int grow = bm + wm + mi*16 + ls*4 + r;
        int gcol = bn + wn + ni*16 + lr;
        float v = acc[mi][ni][r] + bias[gcol] + resid[grow*512 + gcol];
        C[grow*512 + gcol] = v;
      }
}

// ---------------- phases / features: one wave per row ----------------
__global__ __launch_bounds__(256) void k_phase(const float* __restrict__ Hke, const float* __restrict__ Hqe,
                        const float* __restrict__ Hg,
                        const float* __restrict__ kw2, const float* __restrict__ kb2,
                        const float* __restrict__ qw2, const float* __restrict__ qb2,
                        const float* __restrict__ gw2, const float* __restrict__ gb2,
                        const float* __restrict__ setw, const float* __restrict__ posw,
                        const float* __restrict__ freqs,
                        float* __restrict__ ub, float* __restrict__ ab) {
  int t = threadIdx.x;
  int wid = t >> 6, lane = t & 63;
  int r = blockIdx.x*4 + wid;
  int l = r & 1023;
  int p = lane & 15, s = lane >> 4;
  const float* hk = Hke + r*512 + s*128;
  const float* hq = Hqe + r*512 + s*128;
  float kps = 0.f, qps = 0.f;
  for (int i0 = 0; i0 < 128; i0 += 4) {
    float4 hkv = *(const float4*)(hk + i0);
    float4 hqv = *(const float4*)(hq + i0);
    int kb = (s*128 + i0)*16 + p;
    kps += hkv.x * kw2[kb];      qps += hqv.x * qw2[kb];
    kps += hkv.y * kw2[kb+16];   qps += hqv.y * qw2[kb+16];
    kps += hkv.z * kw2[kb+32];   qps += hqv.z * qw2[kb+32];
    kps += hkv.w * kw2[kb+48];   qps += hqv.w * qw2[kb+48];
  }
  kps += __shfl_xor(kps, 16); kps += __shfl_xor(kps, 32);
  qps += __shfl_xor(qps, 16); qps += __shfl_xor(qps, 32);
  const float PI = 3.14159265358979323846f;
  float kph = tanhf(kps + kb2[p]) * PI;
  float qph = tanhf(qps + qb2[p]) * PI;
  const float* hg = Hg + r*256;
  float4 hgv = *(const float4*)(hg + lane*4);
  float gp = hgv.x*gw2[lane*4] + hgv.y*gw2[lane*4+1]
           + hgv.z*gw2[lane*4+2] + hgv.w*gw2[lane*4+3];
  #pragma unroll
  for (int m = 1; m <= 32; m <<= 1) gp += __shfl_xor(gp, m);
  float gate = 1.f/(1.f + expf(-(gp + gb2[0])));
  float pph = (float)l * freqs[p] * 6.2831853071795864769f;
  float s0=setw[0], s1=setw[1], s2=setw[2], s3=setw[3];
  float mx = fmaxf(fmaxf(s0,s1), fmaxf(s2,s3));
  float e0=expf(s0-mx), e1=expf(s1-mx), e2=expf(s2-mx), e3=expf(s3-mx);
  float esum = e0+e1+e2+e3;
  int si = p >> 2;
  float wsel = (si==0? e0 : si==1? e1 : si==2? e2 : e3) / esum;
  float sigpw = 1.f/(1.f + expf(-posw[0]));
  float invnorm = rsqrtf((float)(l+1) * 4.0f);
  if (lane < 16) {
    float sk, ck, sq, cq, sp, cp;
    sincosf(kph, &sk, &ck);
    sincosf(qph, &sq, &cq);
    sincosf(pph, &sp, &cp);
    float* urow = ub + r*64;
    float* arow = ab + r*64;
    urow[p]      = ck;
    urow[16 + p] = sk;
    urow[32 + p] = cp;
    urow[48 + p] = sp;
    float ga = gate * wsel * invnorm;
    float pa = (1.f - gate) * sigpw * invnorm;
    arow[p]      = ga * cq;
    arow[16 + p] = ga * sq;
    arow[32 + p] = pa * cp;
    arow[48 + p] = pa * sp;
  }
}

// ---------------- scan pass A: per-chunk partial sums P[b][c][k][d] ----------------
__global__ __launch_bounds__(256) void k_scanA(const float* __restrict__ ub, const float* __restrict__ V,
                        float* __restrict__ P) {
  __shared__ float ul[CLEN][64];
  __shared__ float vl[CLEN][64];
  int t = threadIdx.x;
  int d0 = blockIdx.x*64; int c = blockIdx.y; int b = blockIdx.z;
  int srow = t >> 2, scol = (t & 3)*16;
  {
    const float* up = ub + (b*1024 + c*CLEN + srow)*64 + scol;
    *(float4*)&ul[srow][scol]    = *(const float4*)up;
    *(float4*)&ul[srow][scol+4]  = *(const float4*)(up+4);
    *(float4*)&ul[srow][scol+8]  = *(const float4*)(up+8);
    *(float4*)&ul[srow][scol+12] = *(const float4*)(up+12);
    const float* vp = V + (b*1024 + c*CLEN + srow)*512 + d0 + scol;
    *(float4*)&vl[srow][scol]    = *(const float4*)vp;
    *(float4*)&vl[srow][scol+4]  = *(const float4*)(vp+4);
    *(float4*)&vl[srow][scol+8]  = *(const float4*)(vp+8);
    *(float4*)&vl[srow][scol+12] = *(const float4*)(vp+12);
  }
  __syncthreads();
  int dd = t & 63, kg = t >> 6;
  float acc[16];
  #pragma unroll
  for (int i=0;i<16;i++) acc[i]=0.f;
  for (int tt = 0; tt < CLEN; tt++) {
    float vv = vl[tt][dd];
    #pragma unroll
    for (int i=0;i<16;i++) acc[i] += ul[tt][kg*16+i]*vv;
  }
  float* pp = P + (((b*NCH + c)*64) + kg*16)*512 + d0 + dd;
  #pragma unroll
  for (int i=0;i<16;i++) pp[i*512] = acc[i];
}

// ---------------- scan pass B: in-place exclusive prefix over chunks ----------------
__global__ __launch_bounds__(256) void k_scanB(float* __restrict__ P) {
  int tid = blockIdx.x*256 + threadIdx.x;   // 0..65535 = B*64*512
  int b = tid >> 15;
  int k = (tid >> 9) & 63;
  int d = tid & 511;
  float run = 0.f;
  float* base = P + ((b*NCH)*64 + k)*512 + d;
  for (int c = 0; c < NCH; c++) {
    float v = base[c*64*512];
    base[c*64*512] = run;
    run += v;
  }
}

// ---------------- scan pass C: intra-chunk sweep, 4 lanes per d, s[16] in regs ----------------
__global__ __launch_bounds__(256) void k_scanC(const float* __restrict__ ub, const float* __restrict__ ab,
                        const float* __restrict__ V, const float* __restrict__ P,
                        float* __restrict__ h) {
  __shared__ float ul[CLEN][64];
  __shared__ float al[CLEN][64];
  int t = threadIdx.x;
  int c = blockIdx.y; int b = blockIdx.z;
  int srow = t >> 2, scol = (t & 3)*16;
  {
    const float* up = ub + (b*1024 + c*CLEN + srow)*64 + scol;
    *(float4*)&ul[srow][scol]    = *(const float4*)up;
    *(float4*)&ul[srow][scol+4]  = *(const float4*)(up+4);
    *(float4*)&ul[srow][scol+8]  = *(const float4*)(up+8);
    *(float4*)&ul[srow][scol+12] = *(const float4*)(up+12);
    const float* ap = ab + (b*1024 + c*CLEN + srow)*64 + scol;
    *(float4*)&al[srow][scol]    = *(const float4*)ap;
    *(float4*)&al[srow][scol+4]  = *(const float4*)(ap+4);
    *(float4*)&al[srow][scol+8]  = *(const float4*)(ap+8);
    *(float4*)&al[srow][scol+12] = *(const float4*)(ap+12);
  }
  __syncthreads();
  int kg = t & 3;          // 4 lanes share one d; each owns 16 features
  int di = t >> 2;         // 0..63
  int d = blockIdx.x*64 + di;
  float s[16];
  const float* pb = P + ((b*NCH + c)*64 + kg*16)*512 + d;
  #pragma unroll
  for (int k = 0; k < 16; k++) s[k] = pb[k*512];
  const float* vrow = V + (b*1024 + c*CLEN)*512 + d;
  float* hrow = h + (b*1024 + c*CLEN)*512 + d;
  const float4* ul4 = (const float4*)&ul[0][0];
  const float4* al4 = (const float4*)&al[0][0];
  for (int tt = 0; tt < CLEN; tt++) {
    float vv = vrow[tt*512];
    float4 u0 = ul4[tt*16 + kg*4 + 0];
    float4 u1 = ul4[tt*16 + kg*4 + 1];
    float4 u2 = ul4[tt*16 + kg*4 + 2];
    float4 u3 = ul4[tt*16 + kg*4 + 3];
    float4 a0 = al4[tt*16 + kg*4 + 0];
    float4 a1 = al4[tt*16 + kg*4 + 1];
    float4 a2 = al4[tt*16 + kg*4 + 2];
    float4 a3 = al4[tt*16 + kg*4 + 3];
    float h0=0.f, h1=0.f, h2=0.f, h3=0.f;
    s[0]  += u0.x*vv; h0 += a0.x*s[0];
    s[1]  += u0.y*vv; h1 += a0.y*s[1];
    s[2]  += u0.z*vv; h2 += a0.z*s[2];
    s[3]  += u0.w*vv; h3 += a0.w*s[3];
    s[4]  += u1.x*vv; h0 += a1.x*s[4];
    s[5]  += u1.y*vv; h1 += a1.y*s[5];
    s[6]  += u1.z*vv; h2 += a1.z*s[6];
    s[7]  += u1.w*vv; h3 += a1.w*s[7];
    s[8]  += u2.x*vv; h0 += a2.x*s[8];
    s[9]  += u2.y*vv; h1 += a2.y*s[9];
    s[10] += u2.z*vv; h2 += a2.z*s[10];
    s[11] += u2.w*vv; h3 += a2.w*s[11];
    s[12] += u3.x*vv; h0 += a3.x*s[12];
    s[13] += u3.y*vv; h1 += a3.y*s[13];
    s[14] += u3.z*vv; h2 += a3.z*s[14];
    s[15] += u3.w*vv; h3 += a3.w*s[15];
    float hp = (h0+h1)+(h2+h3);
    hp += __shfl_xor(hp, 1);
    hp += __shfl_xor(hp, 2);
    if (kg == 0) hrow[tt*512] = hp;
  }
}

// ---------------- layernorm: one wave per row, bf16 out ----------------
__global__ __launch_bounds__(256) void k_ln(const float* __restrict__ h, const float* __restrict__ g,
                     const float* __restrict__ bta, u16* __restrict__ hln) {
  int t = threadIdx.x;
  int wid = t >> 6, lane = t & 63;
  int r = blockIdx.x*4 + wid;
  const float* hr = h + r*512;
  float4 v0 = *(const float4*)(hr + lane*8);
  float4 v1 = *(const float4*)(hr + lane*8 + 4);
  float vals[8] = {v0.x,v0.y,v0.z,v0.w,v1.x,v1.y,v1.z,v1.w};
  float sum = 0.f, sq = 0.f;
  #pragma unroll
  for (int i=0;i<8;i++){ sum += vals[i]; sq += vals[i]*vals[i]; }
  #pragma unroll
  for (int m = 1; m <= 32; m <<= 1){ sum += __shfl_xor(sum, m); sq += __shfl_xor(sq, m); }
  float mu = sum * (1.f/512.f);
  float var = sq * (1.f/512.f) - mu*mu;
  float rstd = rsqrtf(var + 1e-5f);
  unsigned o[4];
  #pragma unroll
  for (int i=0;i<4;i++){
    u16 lo = f2b((vals[2*i]  -mu)*rstd*g[lane*8+2*i]   + bta[lane*8+2*i]);
    u16 hi = f2b((vals[2*i+1]-mu)*rstd*g[lane*8+2*i+1] + bta[lane*8+2*i+1]);
    o[i] = (unsigned)lo | ((unsigned)hi << 16);
  }
  uint4 ov = make_uint4(o[0],o[1],o[2],o[3]);
  *(uint4*)(hln + r*512 + lane*8) = ov;
}

extern "C" void kernel_launch(void* const* d_in, const int* in_sizes, int n_in,
                              void* d_out, int out_size, void* d_ws, size_t ws_size,
                              hipStream_t stream) {
  const float* x       = (const float*)d_in[0];
  const float* ke_w1   = (const float*)d_in[1];
  const float* ke_b1   = (const float*)d_in[2];
  const float* ke_w2   = (const float*)d_in[3];
  const float* ke_b2   = (const float*)d_in[4];
  const float* qe_w1   = (const float*)d_in[5];
  const float* qe_b1   = (const float*)d_in[6];
  const float* qe_w2   = (const float*)d_in[7];
  const float* qe_b2   = (const float*)d_in[8];
  const float* v_w     = (const float*)d_in[9];
  const float* v_b     = (const float*)d_in[10];
  const float* ln_g    = (const float*)d_in[11];
  const float* ln_b    = (const float*)d_in[12];
  const float* out_w   = (const float*)d_in[13];
  const float* out_b   = (const float*)d_in[14];
  const float* setw    = (const float*)d_in[15];
  const float* posw    = (const float*)d_in[16];
  const float* gate_w1 = (const float*)d_in[17];
  const float* gate_b1 = (const float*)d_in[18];
  const float* gate_w2 = (const float*)d_in[19];
  const float* gate_b2 = (const float*)d_in[20];
  const float* freqs   = (const float*)d_in[21];
  float* out = (float*)d_out;

  char* ws = (char*)d_ws;
  u16*   xb  = (u16*)(ws + 0);            // 2048x512 bf16 (2 MB)
  u16*   BTF = (u16*)(ws + 2097152);      // 1792x512 bf16 (1.75 MB)
  u16*   oT  = (u16*)(ws + 3932160);      // 512x512 bf16 (512 KB)
  float* Hke = (float*)(ws + 4456448);    // 2048x512 f32 (reused as h)
  float* Hqe = (float*)(ws + 8650752);    // 2048x512 f32 (reused as hln bf16)
  float* Hg  = (float*)(ws + 12845056);   // 2048x256 f32
  float* V   = (float*)(ws + 14942208);   // 2048x512 f32
  float* ubf = (float*)(ws + 19136512);   // 2048x64 f32
  float* abf = (float*)(ws + 19660800);   // 2048x64 f32
  float* P   = (float*)(ws + 20185088);   // 2*16*64*512 f32 = 4 MB (ends 24379392)
  float* h   = Hke;                       // overlay (Hke consumed by k_phase)
  u16*   hln = (u16*)Hqe;                 // overlay (Hqe consumed by k_phase)

  u16* keT = BTF;                // rows 0..511
  u16* qeT = BTF + 512*512;      // rows 512..1023
  u16* vT  = BTF + 1024*512;     // rows 1024..1535
  u16* gT  = BTF + 1536*512;     // rows 1536..1791

  k_prep<<<512 + 5*256, 256, 0, stream>>>(x, xb, ke_w1,qe_w1,v_w,gate_w1,out_w,
                                          keT,qeT,vT,gT,oT);
  k_gemm4<<<dim3(28,32),256,0,stream>>>(xb, BTF, ke_b1, qe_b1, v_b, gate_b1,
                                        Hke, Hqe, V, Hg);
  k_phase<<<512,256,0,stream>>>(Hke,Hqe,Hg, ke_w2,ke_b2, qe_w2,qe_b2,
                                gate_w2,gate_b2, setw,posw,freqs, ubf,abf);
  k_scanA<<<dim3(8,NCH,2),256,0,stream>>>(ubf, V, P);
  k_scanB<<<256,256,0,stream>>>(P);
  k_scanC<<<dim3(8,NCH,2),256,0,stream>>>(ubf, abf, V, P, h);
  k_ln<<<512,256,0,stream>>>(h, ln_g, ln_b, hln);
  k_gemm_out<<<dim3(8,32),256,0,stream>>>(hln, oT, out_b, x, out);
}